// Round 12
// baseline (254.336 us; speedup 1.0000x reference)
//
#include <hip/hip_runtime.h>

// R20 = R19 (best, 213.7us rocprof) + packed-f32 (v_pk_fma_f32) state math.
// Model (R15/R16/R18/R19-confirmed): SIMD issue-slot bound at 2 waves/SIMD;
// instruction-count cuts pay ~1:1, byte/depth cuts are null.
// CDNA4 has full-rate packed FP32 (VOP3P v_pk_fma/add/mul_f32); LLVM lowers
// <2 x float> arithmetic to it on gfx90a+. All LIF/fc f32 math here was
// scalar -> refactor state to f32x2 pairs:
//  - LIF1 v1/i1/cur1 as f32x2[3]; vd/i-decay as vector exprs (contract->pk).
//  - LIF2 v2/i2 as f32x2[6]; cur2/vd/i2 packed; int Horner stays scalar.
//  - fc: wf as f32x2[9] ({wf0,wf1} pairs), partials f32x2, butterfly adds
//    packed (shuffles stay 2x b32); LIF3 v3/i3 packed.
//  - compares/selects/spike-packing stay scalar via element extract (free).
// ~40 of ~250 VALU issue slots/step/wave removed (-16%). Numerics same
// class (HIP default contraction already chose fma rounding).
// Everything else identical to R19: branchless imm-offset LIF1 scatter,
// 51-row zimg, overlay staging, Tc=2, 9-chain 4x64 GEMM, fc_pair at tail,
// Horner combine, 3-level i8, exact i32 acc. (256,2) -- NEVER raise (R17).

#define NSTEPS 100
#define NCHUNK 50
#define IMSTRIDE 272
#define ZROWS 51               // 48 data rows + 3 trash rows
#define ZIMG (ZROWS * IMSTRIDE)   // 13872 B per buffer; 4 buffers
#define TRASH (48 * IMSTRIDE)  // buffer-relative trash base
#define Z2S 612                // shorts per (sample, step); 68-short pos stride
#define Z2T (4 * Z2S)          // shorts per t-slot
#define Z2PAR (2 * Z2T)        // shorts per chunk parity

typedef __attribute__((ext_vector_type(4))) int i32x4;
typedef __attribute__((ext_vector_type(2))) float f32x2;

// conv1 + 2x2 maxpool for one spike-row (sample, ic, y): 6 outputs
__device__ __forceinline__ void conv1_row(const float* __restrict__ xs,
                                          const float* __restrict__ w1s,
                                          float b1v, int y, float* cur) {
    float cr[2][12];
    #pragma unroll
    for (int rr = 0; rr < 2; ++rr) {
        const int cy = 2 * y + rr;
        #pragma unroll
        for (int cx = 0; cx < 12; ++cx) {
            float a = 0.f;
            #pragma unroll
            for (int ky = 0; ky < 4; ++ky)
            #pragma unroll
            for (int kx = 0; kx < 4; ++kx)
                a = fmaf(xs[(cy + ky) * 16 + cx + kx], w1s[ky * 4 + kx], a);
            cr[rr][cx] = a + b1v;
        }
    }
    #pragma unroll
    for (int px = 0; px < 6; ++px)
        cur[px] = fmaxf(fmaxf(cr[0][2 * px], cr[0][2 * px + 1]),
                        fmaxf(cr[1][2 * px], cr[1][2 * px + 1]));
}

__global__ __launch_bounds__(256, 2)
void snn_kernel(const float* __restrict__ x,
                const float* __restrict__ w1,
                const float* __restrict__ b1,
                const float* __restrict__ w2,
                const float* __restrict__ b2,
                const float* __restrict__ wf,
                const float* __restrict__ bf,
                float* __restrict__ out, int B)
{
    __shared__ __align__(16) unsigned char s_im[4 * ZIMG];       // 55488 B
    __shared__ __align__(16) unsigned short s_z2h[2 * Z2PAR];    // 19584 B

    // overlay: s_x/w1/b1 live only until the pre-loop conv1; the z2h region
    // is first written by GEMM(chunk 0), which is behind barrier(0).
    float* const s_xf = (float*)s_z2h;                  // 4096 B
    float* const s_w1 = (float*)((char*)s_z2h + 4096);  // 832 B
    float* const s_b1 = (float*)((char*)s_z2h + 4928);  // 52 B

    const int tid  = threadIdx.x;
    const int wave = tid >> 6, lane = tid & 63;
    const int quad = lane >> 4, col = lane & 15;

    const f32x2 k01 = {0.1f, 0.1f};
    const f32x2 k08 = {0.8f, 0.8f};

    // ---- stage x / w1 / b1; zero all 4 zimg buffers (incl. trash rows) ----
    ((float4*)(s_xf + wave * 256))[lane] =
        ((const float4*)(x + (size_t)(blockIdx.x * 4 + wave) * 256))[lane];
    if (tid < 208) s_w1[tid] = w1[tid];
    if (tid < 13)  s_b1[tid] = b1[tid];
    for (int i = tid; i < 4 * ZIMG / 16; i += 256)
        ((uint4*)s_im)[i] = make_uint4(0, 0, 0, 0);
    __syncthreads();

    // ---- LIF1 row ownership: rows R = tid and tid+256 of 312 = 4*13*6 ----
    int sA, icA, yA, sB = 0, icB = 0, yB = 0;
    { const int R = tid;       sA = R / 78; int r = R - 78 * sA; icA = r / 6; yA = r - 6 * icA; }
    if (tid < 56) { const int R = tid + 256; sB = R / 78; int r = R - 78 * sB; icB = r / 6; yB = r - 6 * icB; }

    f32x2 cur1a[3], v1a[3], i1a[3], cur1b[3], v1b[3], i1b[3];
    {
        float cu[6];
        conv1_row(s_xf + sA * 256, s_w1 + icA * 16, s_b1[icA], yA, cu);
        #pragma unroll
        for (int j = 0; j < 3; ++j) cur1a[j] = f32x2{cu[2 * j], cu[2 * j + 1]};
    }
    if (tid < 56) {
        float cu[6];
        conv1_row(s_xf + sB * 256, s_w1 + icB * 16, s_b1[icB], yB, cu);
        #pragma unroll
        for (int j = 0; j < 3; ++j) cur1b[j] = f32x2{cu[2 * j], cu[2 * j + 1]};
    }
    #pragma unroll
    for (int j = 0; j < 3; ++j) {
        v1a[j] = f32x2{0.f, 0.f}; i1a[j] = f32x2{0.f, 0.f};
        v1b[j] = f32x2{0.f, 0.f}; i1b[j] = f32x2{0.f, 0.f};
    }

    // ---- branchless scatter bases: buffer-relative dest per ky, or trash ----
    int pbkA[4], pbkB[4];
    #pragma unroll
    for (int ky = 0; ky < 4; ++ky) {
        const int pyA = yA - ky;
        pbkA[ky] = (0 <= pyA && pyA <= 2)
            ? (9 * sA + 3 * pyA) * IMSTRIDE + 16 * icA + 4 * ((ky + icA) & 3)
            : TRASH + 4 * lane;
        const int pyB = yB - ky;
        pbkB[ky] = (0 <= pyB && pyB <= 2)
            ? (9 * sB + 3 * pyB) * IMSTRIDE + 16 * icB + 4 * ((ky + icB) & 3)
            : TRASH + 4 * lane;
    }

    // ---- A-fragments: per-row 3-level i8 split of w2 (sigma-permuted K) ----
    i32x4 A1[4], A2[4], A3[4];
    float Mrow;
    {
        const float* wrow = w2 + (size_t)(wave * 16 + col) * 208;
        float M = 1e-20f;
        for (int k = 0; k < 208; ++k) M = fmaxf(M, fabsf(wrow[k]));
        Mrow = M;
        const float inv = 127.0f / M;
        const float q1s = M * (1.0f / 127.0f);
        const float q2s = M * (1.0f / (127.0f * 127.0f));
        #pragma unroll
        for (int kt = 0; kt < 4; ++kt) {
            i32x4 w1v = {0, 0, 0, 0}, w2v = {0, 0, 0, 0}, w3v = {0, 0, 0, 0};
            #pragma unroll
            for (int j = 0; j < 16; ++j) {
                const int kp = kt * 64 + quad * 16 + j;
                const int W = kp >> 2, kx = kp & 3;
                const int ic = W >> 2, ky = ((W & 3) - ic) & 3;
                const float w = (ic < 13) ? wrow[ic * 16 + ky * 4 + kx] : 0.f;
                const float b1f = rintf(w * inv);
                const float r1  = fmaf(b1f, -q1s, w);
                const float b2f = rintf(r1 * inv * 127.0f);
                const float r2  = fmaf(b2f, -q2s, r1);
                const float b3f = rintf(r2 * inv * 127.0f * 127.0f);
                const int wi = j >> 2, sh = (j & 3) * 8;
                w1v[wi] |= ((int)b1f & 0xFF) << sh;
                w2v[wi] |= ((int)b2f & 0xFF) << sh;
                w3v[wi] |= ((int)b3f & 0xFF) << sh;
            }
            A1[kt] = w1v; A2[kt] = w2v; A3[kt] = w3v;
        }
    }
    // packed per-lane scales (levels fold exactly via integer Horner)
    f32x2 sc3p[2], b2p[2];
    #pragma unroll
    for (int pr = 0; pr < 2; ++pr) {
        const float M0 = __shfl(Mrow, quad * 4 + 2 * pr);
        const float M1 = __shfl(Mrow, quad * 4 + 2 * pr + 1);
        const float s = 1.0f / (127.0f * 127.0f * 127.0f);
        sc3p[pr] = f32x2{M0 * s, M1 * s};
        b2p[pr] = f32x2{b2[wave * 16 + quad * 4 + 2 * pr],
                        b2[wave * 16 + quad * 4 + 2 * pr + 1]};
    }

    // ---- static per-lane: fc weights (packed pairs), B-frag / z2 offsets ----
    f32x2 wf01[9];
    #pragma unroll
    for (int q = 0; q < 9; ++q)
        wf01[q] = f32x2{wf[lane * 9 + q], wf[576 + lane * 9 + q]};
    const f32x2 bfp = {bf[0], bf[1]};

    int bpo[3];        // byte offset of B-frag within a zimg buffer
    int zwo[3];        // short offset of z2 write within a t-slot
    bool zv[3];
    #pragma unroll
    for (int nt = 0; nt < 3; ++nt) {
        const int n = nt * 16 + col;
        bpo[nt] = n * IMSTRIDE + quad * 16;
        zv[nt] = (n < 36);
        const int slz = n / 9, pos = n - slz * 9;
        zwo[nt] = slz * Z2S + pos * 68 + wave * 16 + quad * 4;
    }

    f32x2 v2p[6], i2p[6];
    #pragma unroll
    for (int p = 0; p < 6; ++p) { v2p[p] = f32x2{0.f, 0.f}; i2p[p] = f32x2{0.f, 0.f}; }
    f32x2 v3p = {0.f, 0.f}, i3p = {0.f, 0.f};
    float sum0 = 0.f, sum1 = 0.f;

    const int sG = blockIdx.x * 4 + wave;
    float* outv = out + (size_t)2 * B;

    // LIF1 step (packed) + branchless scatter at compile-time immBase.
    auto lif1_imm = [&](f32x2* v1, f32x2* i1, const f32x2* cur,
                        const int* pbk, int immBase) {
        unsigned zb[6];
        #pragma unroll
        for (int j = 0; j < 3; ++j) {
            const f32x2 t = i1[j] - v1[j];
            const f32x2 vd = v1[j] + t * k01;      // contract -> v_pk_fma
            i1[j] = i1[j] * k08 + cur[j];          // contract -> v_pk_fma
            const bool s0 = vd[0] > 1.0f, s1 = vd[1] > 1.0f;
            v1[j][0] = s0 ? 0.0f : vd[0];
            v1[j][1] = s1 ? 0.0f : vd[1];
            zb[2 * j]     = s0 ? 1u : 0u;
            zb[2 * j + 1] = s1 ? 1u : 0u;
        }
        const unsigned q0 = zb[0] | (zb[1] << 8) | (zb[2] << 16) | (zb[3] << 24);
        const unsigned q1 = zb[1] | (zb[2] << 8) | (zb[3] << 16) | (zb[4] << 24);
        const unsigned q2 = zb[2] | (zb[3] << 8) | (zb[4] << 16) | (zb[5] << 24);
        #pragma unroll
        for (int ky = 0; ky < 4; ++ky) {
            unsigned char* b = s_im + pbk[ky];   // vaddr; rest folds to imm
            *(unsigned*)(b + immBase)                = q0;   // px = 0
            *(unsigned*)(b + immBase + IMSTRIDE)     = q1;   // px = 1
            *(unsigned*)(b + immBase + 2 * IMSTRIDE) = q2;   // px = 2
        }
    };

    // fc + LIF3 for TWO consecutive steps; packed partials/weights/state.
    auto fc_pair = [&](const unsigned short* zsA, int tpA,
                       const unsigned short* zsB, int tpB) {
        f32x2 pa = {0.f, 0.f}, pb = {0.f, 0.f};
        #pragma unroll
        for (int q = 0; q < 9; ++q) {
            const float za = __uint_as_float(((unsigned)zsA[q * 68 + lane]) << 16);
            const float zb = __uint_as_float(((unsigned)zsB[q * 68 + lane]) << 16);
            pa = pa + f32x2{za, za} * wf01[q];     // contract -> v_pk_fma
            pb = pb + f32x2{zb, zb} * wf01[q];
        }
        #pragma unroll
        for (int off = 32; off > 0; off >>= 1) {
            f32x2 qa, qb;
            qa[0] = __shfl_xor(pa[0], off); qa[1] = __shfl_xor(pa[1], off);
            qb[0] = __shfl_xor(pb[0], off); qb[1] = __shfl_xor(pb[1], off);
            pa = pa + qa;                          // v_pk_add
            pb = pb + qb;
        }
        // LIF3 step A
        {
            const f32x2 c3 = pa + bfp;
            const f32x2 t = i3p - v3p;
            const f32x2 vd = v3p + t * k01;
            i3p = i3p * k08 + c3;
            const bool q0 = vd[0] > 1.0f, q1 = vd[1] > 1.0f;
            v3p[0] = q0 ? 0.0f : vd[0];
            v3p[1] = q1 ? 0.0f : vd[1];
            sum0 += q0 ? 1.0f : 0.0f;
            sum1 += q1 ? 1.0f : 0.0f;
            if (lane == 0)
                *(float2*)(outv + (size_t)tpA * 2 * B + 2 * sG) = make_float2(v3p[0], v3p[1]);
        }
        // LIF3 step B
        {
            const f32x2 c3 = pb + bfp;
            const f32x2 t = i3p - v3p;
            const f32x2 vd = v3p + t * k01;
            i3p = i3p * k08 + c3;
            const bool q0 = vd[0] > 1.0f, q1 = vd[1] > 1.0f;
            v3p[0] = q0 ? 0.0f : vd[0];
            v3p[1] = q1 ? 0.0f : vd[1];
            sum0 += q0 ? 1.0f : 0.0f;
            sum1 += q1 ? 1.0f : 0.0f;
            if (lane == 0)
                *(float2*)(outv + (size_t)tpB * 2 * B + 2 * sG) = make_float2(v3p[0], v3p[1]);
        }
    };

    // One chunk (2 timesteps), compile-time parity P at call sites.
    auto chunk = [&](int ch, int P) {
        // ---- Phase A: two LIF1 steps into zimg buffers 2P, 2P+1 ----
        lif1_imm(v1a, i1a, cur1a, pbkA, (2 * P) * ZIMG);
        if (tid < 56) lif1_imm(v1b, i1b, cur1b, pbkB, (2 * P) * ZIMG);
        lif1_imm(v1a, i1a, cur1a, pbkA, (2 * P + 1) * ZIMG);
        if (tid < 56) lif1_imm(v1b, i1b, cur1b, pbkB, (2 * P + 1) * ZIMG);
        __syncthreads();                 // the only barrier per 2 steps

        // ---- GEMM + LIF2: two serial 9-chain passes ----
        #pragma unroll
        for (int tl = 0; tl < 2; ++tl) {
            const unsigned char* zbuf = s_im + (2 * P + tl) * ZIMG;
            i32x4 c1a = {0,0,0,0}, c1b = c1a, c1c = c1a;
            i32x4 c2a = c1a, c2b = c1a, c2c = c1a;
            i32x4 c3a_ = c1a, c3b_ = c1a, c3c = c1a;
            #pragma unroll
            for (int kt = 0; kt < 4; ++kt) {
                const i32x4 B0 = *(const i32x4*)(zbuf + bpo[0] + kt * 64);
                const i32x4 B1 = *(const i32x4*)(zbuf + bpo[1] + kt * 64);
                const i32x4 B2v = *(const i32x4*)(zbuf + bpo[2] + kt * 64);
                c1a = __builtin_amdgcn_mfma_i32_16x16x64_i8(A1[kt], B0,  c1a, 0, 0, 0);
                c1b = __builtin_amdgcn_mfma_i32_16x16x64_i8(A1[kt], B1,  c1b, 0, 0, 0);
                c1c = __builtin_amdgcn_mfma_i32_16x16x64_i8(A1[kt], B2v, c1c, 0, 0, 0);
                c2a = __builtin_amdgcn_mfma_i32_16x16x64_i8(A2[kt], B0,  c2a, 0, 0, 0);
                c2b = __builtin_amdgcn_mfma_i32_16x16x64_i8(A2[kt], B1,  c2b, 0, 0, 0);
                c2c = __builtin_amdgcn_mfma_i32_16x16x64_i8(A2[kt], B2v, c2c, 0, 0, 0);
                c3a_ = __builtin_amdgcn_mfma_i32_16x16x64_i8(A3[kt], B0,  c3a_, 0, 0, 0);
                c3b_ = __builtin_amdgcn_mfma_i32_16x16x64_i8(A3[kt], B1,  c3b_, 0, 0, 0);
                c3c = __builtin_amdgcn_mfma_i32_16x16x64_i8(A3[kt], B2v, c3c, 0, 0, 0);
            }

            const i32x4 L1[3] = {c1a, c1b, c1c};
            const i32x4 L2[3] = {c2a, c2b, c2c};
            const i32x4 L3[3] = {c3a_, c3b_, c3c};
            unsigned short* z2b = s_z2h + P * Z2PAR + tl * Z2T;
            #pragma unroll
            for (int nt = 0; nt < 3; ++nt) {
                unsigned zbits[4];
                #pragma unroll
                for (int pr = 0; pr < 2; ++pr) {
                    const int r0 = 2 * pr, r1 = 2 * pr + 1;
                    // exact integer Horner: c1*127^2 + c2*127 + c3
                    const int ta = __mul24(L1[nt][r0], 127) + L2[nt][r0];
                    const int cia = __mul24(ta, 127) + L3[nt][r0];
                    const int tb = __mul24(L1[nt][r1], 127) + L2[nt][r1];
                    const int cib = __mul24(tb, 127) + L3[nt][r1];
                    const f32x2 cif = {(float)cia, (float)cib};
                    const f32x2 cur2 = sc3p[pr] * cif + b2p[pr];   // pk_fma
                    const int pi = nt * 2 + pr;
                    const f32x2 t = i2p[pi] - v2p[pi];
                    const f32x2 vd = v2p[pi] + t * k01;            // pk_fma
                    i2p[pi] = i2p[pi] * k08 + cur2;                // pk_fma
                    const bool s0 = vd[0] > 1.0f, s1 = vd[1] > 1.0f;
                    v2p[pi][0] = s0 ? 0.0f : vd[0];
                    v2p[pi][1] = s1 ? 0.0f : vd[1];
                    zbits[r0] = s0 ? 0x3F80u : 0u;     // bf16 1.0
                    zbits[r1] = s1 ? 0x3F80u : 0u;
                }
                if (zv[nt]) {
                    const unsigned lo = zbits[0] | (zbits[1] << 16);
                    const unsigned hi = zbits[2] | (zbits[3] << 16);
                    *(uint2*)(z2b + zwo[nt]) = make_uint2(lo, hi);
                }
            }
        }

        // ---- deferred fc at chunk TAIL: both steps of chunk ch-1 (P^1) ----
        if (ch) {
            const unsigned short* zp = s_z2h + (P ^ 1) * Z2PAR + wave * Z2S;
            fc_pair(zp, 2 * ch - 2, zp + Z2T, 2 * ch - 1);
        }
    };

    #pragma unroll 1
    for (int cc = 0; cc < NCHUNK; cc += 2) {
        chunk(cc, 0);
        chunk(cc + 1, 1);
    }

    __syncthreads();
    {   // final chunk (ch=49, P=1) fc
        const unsigned short* zp = s_z2h + 1 * Z2PAR + wave * Z2S;
        fc_pair(zp, NSTEPS - 2, zp + Z2T, NSTEPS - 1);
    }

    if (lane == 0)
        *(float2*)(out + (size_t)2 * sG) = make_float2(sum0, sum1);
}

extern "C" void kernel_launch(void* const* d_in, const int* in_sizes, int n_in,
                              void* d_out, int out_size, void* d_ws, size_t ws_size,
                              hipStream_t stream)
{
    const float* x  = (const float*)d_in[0];
    const float* w1 = (const float*)d_in[1];
    const float* b1 = (const float*)d_in[2];
    const float* w2 = (const float*)d_in[3];
    const float* b2 = (const float*)d_in[4];
    const float* wf = (const float*)d_in[5];
    const float* bf = (const float*)d_in[6];
    float* out = (float*)d_out;

    const int B = in_sizes[0] / 256;     // x is [B,1,16,16]
    const int grid = B / 4;              // 4 samples per block

    hipLaunchKernelGGL(snn_kernel, dim3(grid), dim3(256), 0, stream,
                       x, w1, b1, w2, b2, wf, bf, out, B);
}

// Round 13
// 240.470 us; speedup vs baseline: 1.0577x; 1.0577x over previous
//
#include <hip/hip_runtime.h>

// R21 = R19 (best verified: 213.7us rocprof; R20's f32x2 packing reverted --
// measured null) + DPP wave-reduction in fc.
// Model (R15/R16/R18/R19/R20-fitted): dependency-CHAIN-latency bound at
// 2 waves/SIMD. Chain cuts pay (R15/R16/R19); parallel-inst cuts don't (R20);
// byte/depth cuts don't (R18).
//  - fc butterfly: __shfl_xor = ds_bpermute (~30cy/level, DS pipe) ->
//    v_add_f32_dpp ladder (row_shr 1/2/4/8 + row_bcast 15/31, OOB->0):
//    ~50cy instead of ~200cy serial per chunk, and off the DS pipe that
//    GEMM ds_read_b128 + LIF1 scatter contend on. Result lands in LANE 63
//    (all output writes moved lane 0 -> 63; v3/i3 on other lanes are
//    benign garbage, never read).
// Everything else identical to R19: branchless imm-offset LIF1 scatter,
// 51-row zimg + trash rows, overlay staging, Tc=2, 9-chain 4x64 GEMM,
// fc_pair at chunk tail, Horner combine, 3-level i8, exact i32 acc.
// (256,2) -- NEVER raise (R9/R11/R17: allocator even-split -> spill).

#define NSTEPS 100
#define NCHUNK 50
#define IMSTRIDE 272
#define ZROWS 51               // 48 data rows + 3 trash rows
#define ZIMG (ZROWS * IMSTRIDE)   // 13872 B per buffer; 4 buffers
#define TRASH (48 * IMSTRIDE)  // buffer-relative trash base
#define Z2S 612                // shorts per (sample, step); 68-short pos stride
#define Z2T (4 * Z2S)          // shorts per t-slot
#define Z2PAR (2 * Z2T)        // shorts per chunk parity

typedef __attribute__((ext_vector_type(4))) int i32x4;

// one DPP reduce level: p += dpp_mov(p, CTRL), out-of-bounds lanes read 0.
// CTRL: 0x111/0x112/0x114/0x118 = row_shr:1/2/4/8, 0x142/0x143 = row_bcast:15/31
template <int CTRL>
__device__ __forceinline__ float dpp_add(float p) {
    const int t = __builtin_amdgcn_update_dpp(
        0, __float_as_int(p), CTRL, 0xf, 0xf, true);
    return p + __int_as_float(t);
}

// conv1 + 2x2 maxpool for one spike-row (sample, ic, y): 6 outputs
__device__ __forceinline__ void conv1_row(const float* __restrict__ xs,
                                          const float* __restrict__ w1s,
                                          float b1v, int y, float* cur) {
    float cr[2][12];
    #pragma unroll
    for (int rr = 0; rr < 2; ++rr) {
        const int cy = 2 * y + rr;
        #pragma unroll
        for (int cx = 0; cx < 12; ++cx) {
            float a = 0.f;
            #pragma unroll
            for (int ky = 0; ky < 4; ++ky)
            #pragma unroll
            for (int kx = 0; kx < 4; ++kx)
                a = fmaf(xs[(cy + ky) * 16 + cx + kx], w1s[ky * 4 + kx], a);
            cr[rr][cx] = a + b1v;
        }
    }
    #pragma unroll
    for (int px = 0; px < 6; ++px)
        cur[px] = fmaxf(fmaxf(cr[0][2 * px], cr[0][2 * px + 1]),
                        fmaxf(cr[1][2 * px], cr[1][2 * px + 1]));
}

__global__ __launch_bounds__(256, 2)
void snn_kernel(const float* __restrict__ x,
                const float* __restrict__ w1,
                const float* __restrict__ b1,
                const float* __restrict__ w2,
                const float* __restrict__ b2,
                const float* __restrict__ wf,
                const float* __restrict__ bf,
                float* __restrict__ out, int B)
{
    __shared__ __align__(16) unsigned char s_im[4 * ZIMG];       // 55488 B
    __shared__ __align__(16) unsigned short s_z2h[2 * Z2PAR];    // 19584 B

    // overlay: s_x/w1/b1 live only until the pre-loop conv1; the z2h region
    // is first written by GEMM(chunk 0), which is behind barrier(0).
    float* const s_xf = (float*)s_z2h;                  // 4096 B
    float* const s_w1 = (float*)((char*)s_z2h + 4096);  // 832 B
    float* const s_b1 = (float*)((char*)s_z2h + 4928);  // 52 B

    const int tid  = threadIdx.x;
    const int wave = tid >> 6, lane = tid & 63;
    const int quad = lane >> 4, col = lane & 15;

    // ---- stage x / w1 / b1; zero all 4 zimg buffers (incl. trash rows) ----
    ((float4*)(s_xf + wave * 256))[lane] =
        ((const float4*)(x + (size_t)(blockIdx.x * 4 + wave) * 256))[lane];
    if (tid < 208) s_w1[tid] = w1[tid];
    if (tid < 13)  s_b1[tid] = b1[tid];
    for (int i = tid; i < 4 * ZIMG / 16; i += 256)
        ((uint4*)s_im)[i] = make_uint4(0, 0, 0, 0);
    __syncthreads();

    // ---- LIF1 row ownership: rows R = tid and tid+256 of 312 = 4*13*6 ----
    int sA, icA, yA, sB = 0, icB = 0, yB = 0;
    { const int R = tid;       sA = R / 78; int r = R - 78 * sA; icA = r / 6; yA = r - 6 * icA; }
    if (tid < 56) { const int R = tid + 256; sB = R / 78; int r = R - 78 * sB; icB = r / 6; yB = r - 6 * icB; }

    float cur1a[6], v1a[6], i1a[6], cur1b[6], v1b[6], i1b[6];
    conv1_row(s_xf + sA * 256, s_w1 + icA * 16, s_b1[icA], yA, cur1a);
    if (tid < 56) conv1_row(s_xf + sB * 256, s_w1 + icB * 16, s_b1[icB], yB, cur1b);
    #pragma unroll
    for (int j = 0; j < 6; ++j) { v1a[j] = i1a[j] = 0.f; v1b[j] = i1b[j] = 0.f; }

    // ---- branchless scatter bases: buffer-relative dest per ky, or trash ----
    int pbkA[4], pbkB[4];
    #pragma unroll
    for (int ky = 0; ky < 4; ++ky) {
        const int pyA = yA - ky;
        pbkA[ky] = (0 <= pyA && pyA <= 2)
            ? (9 * sA + 3 * pyA) * IMSTRIDE + 16 * icA + 4 * ((ky + icA) & 3)
            : TRASH + 4 * lane;
        const int pyB = yB - ky;
        pbkB[ky] = (0 <= pyB && pyB <= 2)
            ? (9 * sB + 3 * pyB) * IMSTRIDE + 16 * icB + 4 * ((ky + icB) & 3)
            : TRASH + 4 * lane;
    }

    // ---- A-fragments: per-row 3-level i8 split of w2 (sigma-permuted K) ----
    i32x4 A1[4], A2[4], A3[4];
    float Mrow;
    {
        const float* wrow = w2 + (size_t)(wave * 16 + col) * 208;
        float M = 1e-20f;
        for (int k = 0; k < 208; ++k) M = fmaxf(M, fabsf(wrow[k]));
        Mrow = M;
        const float inv = 127.0f / M;
        const float q1s = M * (1.0f / 127.0f);
        const float q2s = M * (1.0f / (127.0f * 127.0f));
        #pragma unroll
        for (int kt = 0; kt < 4; ++kt) {
            i32x4 w1v = {0, 0, 0, 0}, w2v = {0, 0, 0, 0}, w3v = {0, 0, 0, 0};
            #pragma unroll
            for (int j = 0; j < 16; ++j) {
                const int kp = kt * 64 + quad * 16 + j;
                const int W = kp >> 2, kx = kp & 3;
                const int ic = W >> 2, ky = ((W & 3) - ic) & 3;
                const float w = (ic < 13) ? wrow[ic * 16 + ky * 4 + kx] : 0.f;
                const float b1f = rintf(w * inv);
                const float r1  = fmaf(b1f, -q1s, w);
                const float b2f = rintf(r1 * inv * 127.0f);
                const float r2  = fmaf(b2f, -q2s, r1);
                const float b3f = rintf(r2 * inv * 127.0f * 127.0f);
                const int wi = j >> 2, sh = (j & 3) * 8;
                w1v[wi] |= ((int)b1f & 0xFF) << sh;
                w2v[wi] |= ((int)b2f & 0xFF) << sh;
                w3v[wi] |= ((int)b3f & 0xFF) << sh;
            }
            A1[kt] = w1v; A2[kt] = w2v; A3[kt] = w3v;
        }
    }
    // single per-lane scale: levels fold exactly via integer Horner combine
    float sc3[4];
    #pragma unroll
    for (int r = 0; r < 4; ++r) {
        const float Mr = __shfl(Mrow, quad * 4 + r);
        sc3[r] = Mr * (1.0f / (127.0f * 127.0f * 127.0f));
    }

    // ---- static per-lane: fc weights, b2, B-frag / z2 offsets ----
    float wf0[9], wf1[9];
    #pragma unroll
    for (int q = 0; q < 9; ++q) {
        wf0[q] = wf[lane * 9 + q];          // fc reads z2h[q*68 + lane] (oc=lane)
        wf1[q] = wf[576 + lane * 9 + q];
    }
    const float bfv0 = bf[0], bfv1 = bf[1];
    float b2r[4];
    #pragma unroll
    for (int r = 0; r < 4; ++r) b2r[r] = b2[wave * 16 + quad * 4 + r];

    int bpo[3];        // byte offset of B-frag within a zimg buffer
    int zwo[3];        // short offset of z2 write within a t-slot
    bool zv[3];
    #pragma unroll
    for (int nt = 0; nt < 3; ++nt) {
        const int n = nt * 16 + col;
        bpo[nt] = n * IMSTRIDE + quad * 16;
        zv[nt] = (n < 36);
        const int slz = n / 9, pos = n - slz * 9;
        zwo[nt] = slz * Z2S + pos * 68 + wave * 16 + quad * 4;
    }

    float v2[12], i2[12];
    #pragma unroll
    for (int p = 0; p < 12; ++p) { v2[p] = 0.f; i2[p] = 0.f; }
    float v3a = 0.f, i3a = 0.f, v3b = 0.f, i3b = 0.f, sum0 = 0.f, sum1 = 0.f;

    const int sG = blockIdx.x * 4 + wave;
    float* outv = out + (size_t)2 * B;

    // fc + LIF3 for TWO consecutive steps: independent dot-products, one
    // DPP reduction ladder with 4 interleaved chains (total lands in lane
    // 63), then the two serial LIF3 updates.
    auto fc_pair = [&](const unsigned short* zsA, int tpA,
                       const unsigned short* zsB, int tpB) {
        float p0a = 0.f, p1a = 0.f, p0b = 0.f, p1b = 0.f;
        #pragma unroll
        for (int q = 0; q < 9; ++q) {
            const float za = __uint_as_float(((unsigned)zsA[q * 68 + lane]) << 16);
            const float zb = __uint_as_float(((unsigned)zsB[q * 68 + lane]) << 16);
            p0a = fmaf(za, wf0[q], p0a);
            p1a = fmaf(za, wf1[q], p1a);
            p0b = fmaf(zb, wf0[q], p0b);
            p1b = fmaf(zb, wf1[q], p1b);
        }
        // DPP reduce: row_shr 1/2/4/8 then row_bcast 15/31; total in lane 63.
        p0a = dpp_add<0x111>(p0a); p1a = dpp_add<0x111>(p1a);
        p0b = dpp_add<0x111>(p0b); p1b = dpp_add<0x111>(p1b);
        p0a = dpp_add<0x112>(p0a); p1a = dpp_add<0x112>(p1a);
        p0b = dpp_add<0x112>(p0b); p1b = dpp_add<0x112>(p1b);
        p0a = dpp_add<0x114>(p0a); p1a = dpp_add<0x114>(p1a);
        p0b = dpp_add<0x114>(p0b); p1b = dpp_add<0x114>(p1b);
        p0a = dpp_add<0x118>(p0a); p1a = dpp_add<0x118>(p1a);
        p0b = dpp_add<0x118>(p0b); p1b = dpp_add<0x118>(p1b);
        p0a = dpp_add<0x142>(p0a); p1a = dpp_add<0x142>(p1a);
        p0b = dpp_add<0x142>(p0b); p1b = dpp_add<0x142>(p1b);
        p0a = dpp_add<0x143>(p0a); p1a = dpp_add<0x143>(p1a);
        p0b = dpp_add<0x143>(p0b); p1b = dpp_add<0x143>(p1b);
        // LIF3 step A (valid on lane 63; other lanes benign garbage)
        {
            const float c3a = p0a + bfv0, c3b = p1a + bfv1;
            const float vd0 = v3a + 0.1f * (i3a - v3a);
            const float vd1 = v3b + 0.1f * (i3b - v3b);
            i3a = i3a * 0.8f + c3a;
            i3b = i3b * 0.8f + c3b;
            const bool q0 = vd0 > 1.0f, q1 = vd1 > 1.0f;
            v3a = q0 ? 0.0f : vd0;
            v3b = q1 ? 0.0f : vd1;
            sum0 += q0 ? 1.0f : 0.0f;
            sum1 += q1 ? 1.0f : 0.0f;
            if (lane == 63)
                *(float2*)(outv + (size_t)tpA * 2 * B + 2 * sG) = make_float2(v3a, v3b);
        }
        // LIF3 step B
        {
            const float c3a = p0b + bfv0, c3b = p1b + bfv1;
            const float vd0 = v3a + 0.1f * (i3a - v3a);
            const float vd1 = v3b + 0.1f * (i3b - v3b);
            i3a = i3a * 0.8f + c3a;
            i3b = i3b * 0.8f + c3b;
            const bool q0 = vd0 > 1.0f, q1 = vd1 > 1.0f;
            v3a = q0 ? 0.0f : vd0;
            v3b = q1 ? 0.0f : vd1;
            sum0 += q0 ? 1.0f : 0.0f;
            sum1 += q1 ? 1.0f : 0.0f;
            if (lane == 63)
                *(float2*)(outv + (size_t)tpB * 2 * B + 2 * sG) = make_float2(v3a, v3b);
        }
    };

    // LIF1 step + branchless scatter into buffer at compile-time immBase.
    auto lif1_imm = [&](float* v1, float* i1, const float* cur,
                        const int* pbk, int immBase) {
        unsigned zb[6];
        #pragma unroll
        for (int xx = 0; xx < 6; ++xx) {
            const float vd = v1[xx] + 0.1f * (i1[xx] - v1[xx]);
            i1[xx] = i1[xx] * 0.8f + cur[xx];
            const bool sp = vd > 1.0f;
            v1[xx] = sp ? 0.0f : vd;
            zb[xx] = sp ? 1u : 0u;
        }
        const unsigned q0 = zb[0] | (zb[1] << 8) | (zb[2] << 16) | (zb[3] << 24);
        const unsigned q1 = zb[1] | (zb[2] << 8) | (zb[3] << 16) | (zb[4] << 24);
        const unsigned q2 = zb[2] | (zb[3] << 8) | (zb[4] << 16) | (zb[5] << 24);
        #pragma unroll
        for (int ky = 0; ky < 4; ++ky) {
            unsigned char* b = s_im + pbk[ky];   // vaddr; rest folds to imm
            *(unsigned*)(b + immBase)                = q0;   // px = 0
            *(unsigned*)(b + immBase + IMSTRIDE)     = q1;   // px = 1
            *(unsigned*)(b + immBase + 2 * IMSTRIDE) = q2;   // px = 2
        }
    };

    // One chunk (2 timesteps), compile-time parity P at call sites.
    auto chunk = [&](int ch, int P) {
        // ---- Phase A: two LIF1 steps into zimg buffers 2P, 2P+1 ----
        lif1_imm(v1a, i1a, cur1a, pbkA, (2 * P) * ZIMG);
        if (tid < 56) lif1_imm(v1b, i1b, cur1b, pbkB, (2 * P) * ZIMG);
        lif1_imm(v1a, i1a, cur1a, pbkA, (2 * P + 1) * ZIMG);
        if (tid < 56) lif1_imm(v1b, i1b, cur1b, pbkB, (2 * P + 1) * ZIMG);
        __syncthreads();                 // the only barrier per 2 steps

        // ---- GEMM + LIF2: two serial 9-chain passes ----
        #pragma unroll
        for (int tl = 0; tl < 2; ++tl) {
            const unsigned char* zbuf = s_im + (2 * P + tl) * ZIMG;
            i32x4 c1a = {0,0,0,0}, c1b = c1a, c1c = c1a;
            i32x4 c2a = c1a, c2b = c1a, c2c = c1a;
            i32x4 c3a_ = c1a, c3b_ = c1a, c3c = c1a;
            #pragma unroll
            for (int kt = 0; kt < 4; ++kt) {
                const i32x4 B0 = *(const i32x4*)(zbuf + bpo[0] + kt * 64);
                const i32x4 B1 = *(const i32x4*)(zbuf + bpo[1] + kt * 64);
                const i32x4 B2v = *(const i32x4*)(zbuf + bpo[2] + kt * 64);
                c1a = __builtin_amdgcn_mfma_i32_16x16x64_i8(A1[kt], B0,  c1a, 0, 0, 0);
                c1b = __builtin_amdgcn_mfma_i32_16x16x64_i8(A1[kt], B1,  c1b, 0, 0, 0);
                c1c = __builtin_amdgcn_mfma_i32_16x16x64_i8(A1[kt], B2v, c1c, 0, 0, 0);
                c2a = __builtin_amdgcn_mfma_i32_16x16x64_i8(A2[kt], B0,  c2a, 0, 0, 0);
                c2b = __builtin_amdgcn_mfma_i32_16x16x64_i8(A2[kt], B1,  c2b, 0, 0, 0);
                c2c = __builtin_amdgcn_mfma_i32_16x16x64_i8(A2[kt], B2v, c2c, 0, 0, 0);
                c3a_ = __builtin_amdgcn_mfma_i32_16x16x64_i8(A3[kt], B0,  c3a_, 0, 0, 0);
                c3b_ = __builtin_amdgcn_mfma_i32_16x16x64_i8(A3[kt], B1,  c3b_, 0, 0, 0);
                c3c = __builtin_amdgcn_mfma_i32_16x16x64_i8(A3[kt], B2v, c3c, 0, 0, 0);
            }

            const i32x4 L1[3] = {c1a, c1b, c1c};
            const i32x4 L2[3] = {c2a, c2b, c2c};
            const i32x4 L3[3] = {c3a_, c3b_, c3c};
            unsigned short* z2b = s_z2h + P * Z2PAR + tl * Z2T;
            #pragma unroll
            for (int nt = 0; nt < 3; ++nt) {
                unsigned zbits[4];
                #pragma unroll
                for (int r = 0; r < 4; ++r) {
                    const int p = nt * 4 + r;
                    // exact integer Horner: c1*127^2 + c2*127 + c3, then one
                    // cvt + one fma (ranges: |c1|<=26416, |t1|<=3.38M < 2^23)
                    const int t1 = __mul24(L1[nt][r], 127) + L2[nt][r];
                    const int ci = __mul24(t1, 127) + L3[nt][r];
                    const float cur2 = fmaf(sc3[r], (float)ci, b2r[r]);
                    const float vd = v2[p] + 0.1f * (i2[p] - v2[p]);
                    i2[p] = i2[p] * 0.8f + cur2;
                    const bool sp = vd > 1.0f;
                    v2[p] = sp ? 0.0f : vd;
                    zbits[r] = sp ? 0x3F80u : 0u;     // bf16 1.0
                }
                if (zv[nt]) {
                    const unsigned lo = zbits[0] | (zbits[1] << 16);
                    const unsigned hi = zbits[2] | (zbits[3] << 16);
                    *(uint2*)(z2b + zwo[nt]) = make_uint2(lo, hi);
                }
            }
        }

        // ---- deferred fc at chunk TAIL: both steps of chunk ch-1 (P^1) ----
        // Reads separated from GEMM(ch-1) writes by barrier(ch); next writer
        // of those slots is GEMM(ch+1), after barrier(ch+1).
        if (ch) {
            const unsigned short* zp = s_z2h + (P ^ 1) * Z2PAR + wave * Z2S;
            fc_pair(zp, 2 * ch - 2, zp + Z2T, 2 * ch - 1);
        }
    };

    #pragma unroll 1
    for (int cc = 0; cc < NCHUNK; cc += 2) {
        chunk(cc, 0);
        chunk(cc + 1, 1);
    }

    __syncthreads();
    {   // final chunk (ch=49, P=1) fc
        const unsigned short* zp = s_z2h + 1 * Z2PAR + wave * Z2S;
        fc_pair(zp, NSTEPS - 2, zp + Z2T, NSTEPS - 1);
    }

    if (lane == 63)
        *(float2*)(out + (size_t)2 * sG) = make_float2(sum0, sum1);
}

extern "C" void kernel_launch(void* const* d_in, const int* in_sizes, int n_in,
                              void* d_out, int out_size, void* d_ws, size_t ws_size,
                              hipStream_t stream)
{
    const float* x  = (const float*)d_in[0];
    const float* w1 = (const float*)d_in[1];
    const float* b1 = (const float*)d_in[2];
    const float* w2 = (const float*)d_in[3];
    const float* b2 = (const float*)d_in[4];
    const float* wf = (const float*)d_in[5];
    const float* bf = (const float*)d_in[6];
    float* out = (float*)d_out;

    const int B = in_sizes[0] / 256;     // x is [B,1,16,16]
    const int grid = B / 4;              // 4 samples per block

    hipLaunchKernelGGL(snn_kernel, dim3(grid), dim3(256), 0, stream,
                       x, w1, b1, w2, b2, wf, bf, out, B);
}